// Round 13
// baseline (113.182 us; speedup 1.0000x reference)
//
#include <hip/hip_runtime.h>
#include <cstdint>
#include <initializer_list>

// Problem constants
#define B_   256   // BATCH
#define N_   256   // NODE_NUM
#define S_   128   // SEQ_LEN
#define Fm1  63    // FEATURE_NUM-1
#define XROW 65    // FEATURE_NUM+1 (x last-dim)
#define H1   512   // HIDDEN/2
#define H2   1024  // HIDDEN
#define FCH  512   // FC_HIDDEN
#define NCAP 64    // neighbor capacity (cnt ~26 +- 4.7; 64 is ~8 sigma)

typedef __attribute__((ext_vector_type(8))) short short8;
typedef __attribute__((ext_vector_type(4))) float f32x4;

__device__ __forceinline__ unsigned short f2bf(float f) {
    union { float f; unsigned u; } v; v.f = f;
    unsigned r = v.u + 0x7FFF + ((v.u >> 16) & 1);   // RNE
    return (unsigned short)(r >> 16);
}
__device__ __forceinline__ float bf2f(unsigned short u) {
    union { unsigned u; float f; } v; v.u = ((unsigned)u) << 16;
    return v.f;
}

// ---------------- single init launch ----------------
// blocks [0,4096):        weight transposes (z = blk>>10, by, bx)
// blocks [4096,4352):     An row n = blk-4096 (local dinv)
// blocks [4352,4416):     neighbor lists, 4 samples each (local dinv)
// block  4416:            zero BN accumulators
// blocks [4417,4673):     zero+scatter sample b = blk-4417
__global__ void k_init(const float* __restrict__ W1, const float* __restrict__ W2,
                       const float* __restrict__ W3, const float* __restrict__ fcW1,
                       const float* __restrict__ adj, const float* __restrict__ x,
                       unsigned short* __restrict__ W1T, unsigned short* __restrict__ W2T,
                       unsigned short* __restrict__ W3T, unsigned short* __restrict__ fcW1T,
                       float* __restrict__ mv,
                       unsigned short* __restrict__ Anb,
                       int* __restrict__ nidx, float* __restrict__ nw,
                       unsigned short* __restrict__ Xs) {
    int blk = blockIdx.x;
    int tid = threadIdx.x;
    if (blk < 4096) {
        // ---- weight transpose ----
        const float* in; unsigned short* out; int R_in, C_in, R_pad;
        switch (blk >> 10) {
            case 0:  in = W1;   out = W1T;   R_in = Fm1; C_in = H1; R_pad = 64;  break;
            case 1:  in = W2;   out = W2T;   R_in = H1;  C_in = H1; R_pad = H1;  break;
            case 2:  in = W3;   out = W3T;   R_in = H1;  C_in = H2; R_pad = H1;  break;
            default: in = fcW1; out = fcW1T; R_in = H2;  C_in = H1; R_pad = H2;  break;
        }
        int r0 = ((blk >> 5) & 31) * 32, c0 = (blk & 31) * 32;
        if (r0 >= R_pad || c0 >= C_in) return;
        __shared__ float tile[32][33];
        int tr = tid >> 5, tc = tid & 31;   // 8 x 32
#pragma unroll
        for (int rr = 0; rr < 4; ++rr) {
            int r = r0 + tr + rr * 8;
            tile[tr + rr * 8][tc] = (r < R_in) ? in[(size_t)r * C_in + c0 + tc] : 0.f;
        }
        __syncthreads();
#pragma unroll
        for (int rr = 0; rr < 4; ++rr) {
            int c = c0 + tr + rr * 8;
            int r = r0 + tc;
            out[(size_t)c * R_pad + r] = f2bf(tile[tc][tr + rr * 8]);
        }
        return;
    }
    if (blk < 4416) {
        // ---- An rows / neighbor lists, with block-local dinv ----
        __shared__ float dl[N_];
        {
            const float4* ap = (const float4*)(adj + (size_t)tid * N_);
            float s = 0.f;
#pragma unroll 8
            for (int i2 = 0; i2 < 64; ++i2) {
                float4 v4 = ap[i2];
                s += v4.x + v4.y + v4.z + v4.w;
            }
            dl[tid] = rsqrtf(s + 1.0f);   // deterministic, identical in every block
        }
        __syncthreads();
        if (blk < 4352) {
            int n = blk - 4096;
            float a = adj[n * N_ + tid] + (n == tid ? 1.f : 0.f);
            Anb[n * N_ + tid] = f2bf(a * dl[n] * dl[tid]);
        } else {
            int w = tid >> 6, lane = tid & 63;
            int b = (blk - 4352) * 4 + w;
            int g = (int)x[((size_t)b * S_ + S_ - 1) * XROW + (XROW - 2)];
            float dg = dl[g];
            int base = 0;
            for (int c = 0; c < 4; ++c) {
                int m = c * 64 + lane;
                float a = adj[g * N_ + m] + (g == m ? 1.f : 0.f);
                float v = a * dg * dl[m];   // identical expression to the An path
                unsigned long long mask = __ballot(v != 0.f);
                int pos = __popcll(mask & ((1ull << lane) - 1ull));
                if (v != 0.f) {
                    int s = base + pos;
                    if (s < NCAP) { nidx[b * NCAP + s] = m; nw[b * NCAP + s] = v; }
                }
                base += __popcll(mask);
            }
            for (int s = base + lane; s < NCAP; s += 64) {
                nidx[b * NCAP + s] = 0;
                nw[b * NCAP + s] = 0.f;
            }
        }
        return;
    }
    if (blk == 4416) {
        for (int k = tid; k < 1024; k += 256) mv[k] = 0.f;
        return;
    }
    // ---- zero+scatter: block writes ALL 256 node rows of sample b ----
    int b = blk - 4417;
    __shared__ short pres[N_];   // node -> seq index j, or -1
    pres[tid] = -1;
    __syncthreads();
    if (tid < S_) {
        int s = (int)x[((size_t)b * S_ + tid) * XROW + (XROW - 2)];
        pres[s] = (short)tid;    // sid unique per sample (permutation slice)
    }
    __syncthreads();
#pragma unroll
    for (int pass = 0; pass < 8; ++pass) {
        int m = pass * 32 + (tid >> 3);
        int f8 = tid & 7;
        int j = pres[m];
        unsigned short o[8];
        if (j >= 0) {
            const float* src = x + ((size_t)b * S_ + j) * XROW + f8 * 8;
#pragma unroll
            for (int i = 0; i < 8; ++i) {
                int f = f8 * 8 + i;
                o[i] = (f < Fm1) ? f2bf(src[i]) : (unsigned short)0;
            }
        } else {
#pragma unroll
            for (int i = 0; i < 8; ++i) o[i] = 0;
        }
        *(uint4*)(Xs + ((size_t)m * B_ + b) * 64 + f8 * 8) = *(uint4*)o;
    }
}

// ---------------- packing bgemm (GEMM0 only: B row-major [K,N]) ----------------
template <int ACT, int BIAS>
__global__ __launch_bounds__(256) void bgemm(const unsigned short* __restrict__ A,
                                             const unsigned short* __restrict__ B,
                                             const float* __restrict__ bias,
                                             unsigned short* __restrict__ C,
                                             int K, int lda, int ldb, int ldc) {
    __shared__ unsigned short Abuf[2][4][128][8];
    __shared__ unsigned short Bbuf[2][4][128][8];
    int tid = threadIdx.x;
    int bm = blockIdx.y * 128, bn = blockIdx.x * 128;
    int wid = tid >> 6, lane = tid & 63;
    int wr = wid >> 1, wc = wid & 1;
    int arow = tid >> 1, ahalf = tid & 1;
    int bcol = (tid & 63) * 2, bkb = tid >> 6;
    f32x4 acc[4][4] = {};
    uint4 areg0, areg1;
    unsigned br0[4], br1[4];
    const int nt = K / 32;
    auto gload = [&](int t) {
        int k0 = t * 32;
        const unsigned short* ap = A + (size_t)(bm + arow) * lda + k0 + ahalf * 16;
        areg0 = *(const uint4*)(ap);
        areg1 = *(const uint4*)(ap + 8);
        const unsigned short* bp = B + (size_t)(k0 + bkb * 8) * ldb + bn + bcol;
#pragma unroll
        for (int jj = 0; jj < 4; ++jj) {
            unsigned lo = *(const unsigned*)(bp);
            unsigned hi = *(const unsigned*)(bp + ldb);
            br0[jj] = (lo & 0xffffu) | (hi << 16);
            br1[jj] = (lo >> 16) | (hi & 0xffff0000u);
            bp += 2 * (size_t)ldb;
        }
    };
    auto swrite = [&](int buf) {
        *(uint4*)(&Abuf[buf][ahalf * 2 + 0][arow][0]) = areg0;
        *(uint4*)(&Abuf[buf][ahalf * 2 + 1][arow][0]) = areg1;
        *(uint4*)(&Bbuf[buf][bkb][bcol][0]) = *(uint4*)br0;
        *(uint4*)(&Bbuf[buf][bkb][bcol + 1][0]) = *(uint4*)br1;
    };
    gload(0);
    swrite(0);
    __syncthreads();
    for (int t = 0; t < nt; ++t) {
        if (t + 1 < nt) gload(t + 1);
        int buf = t & 1;
        int kb = lane >> 4, lr = lane & 15;
        short8 af[4], bfr[4];
#pragma unroll
        for (int i = 0; i < 4; ++i)
            af[i] = *(const short8*)(&Abuf[buf][kb][wr * 64 + i * 16 + lr][0]);
#pragma unroll
        for (int j = 0; j < 4; ++j)
            bfr[j] = *(const short8*)(&Bbuf[buf][kb][wc * 64 + j * 16 + lr][0]);
#pragma unroll
        for (int i = 0; i < 4; ++i)
#pragma unroll
            for (int j = 0; j < 4; ++j)
                acc[i][j] = __builtin_amdgcn_mfma_f32_16x16x32_bf16(
                    af[i], bfr[j], acc[i][j], 0, 0, 0);
        if (t + 1 < nt) swrite(buf ^ 1);
        __syncthreads();
    }
    int lr = lane & 15, rg = lane >> 4;
#pragma unroll
    for (int j = 0; j < 4; ++j) {
        int col = bn + wc * 64 + j * 16 + lr;
        float bv = BIAS ? bias[col] : 0.f;
#pragma unroll
        for (int i = 0; i < 4; ++i) {
            int row0 = bm + wr * 64 + i * 16 + rg * 4;
#pragma unroll
            for (int r = 0; r < 4; ++r) {
                float v = acc[i][j][r] + bv;
                if (ACT) v = fmaxf(v, 0.f);
                C[(size_t)(row0 + r) * ldc + col] = f2bf(v);
            }
        }
    }
}

// ---------------- bt-GEMM (m97 structure): C = act(A @ B^T + bias) ----------------
// BNACC: epilogue accumulates per-column sum/sumsq into bnacc[col], bnacc[FCH+col]
template <int ACT, int BIASMODE, int OUTF32, int BNACC>
__global__ __launch_bounds__(256) void btgemm(const unsigned short* __restrict__ A,
                                              const unsigned short* __restrict__ Bm,
                                              const float* __restrict__ bias,
                                              void* __restrict__ Cv,
                                              float* __restrict__ bnacc,
                                              int K, int lda, int ldb, int ldc,
                                              int ns, int sb, int sc) {
    __shared__ unsigned short Ab[2][128][32];
    __shared__ unsigned short Bb[2][128][32];
    int tid = threadIdx.x;
    int bm = blockIdx.y * 128;
    int bx = blockIdx.x;
    int sample = bx >> ns;
    int bn = (bx & ((1 << ns) - 1)) * 128;
    const unsigned short* Bp = Bm + (size_t)sample * sb;
    size_t coff = (size_t)sample * sc;

    int wid = tid >> 6, lane = tid & 63;
    int wr = wid >> 1, wc = wid & 1;
    int c0 = wid * 2;
    int lrow = lane >> 2, lkq = lane & 3;

    f32x4 acc[4][4] = {};
    const int nt = K / 32;

    auto STAGE = [&](int t, int buf) {
        int k0 = t * 32;
#pragma unroll
        for (int i = 0; i < 2; ++i) {
            int row = (c0 + i) * 16 + lrow;
            const unsigned short* ga = A + (size_t)(bm + row) * lda + k0 + lkq * 8;
            __builtin_amdgcn_global_load_lds(
                (const __attribute__((address_space(1))) unsigned int*)ga,
                (__attribute__((address_space(3))) unsigned int*)&Ab[buf][(c0 + i) * 16][0],
                16, 0, 0);
            const unsigned short* gb = Bp + (size_t)(bn + row) * ldb + k0 + lkq * 8;
            __builtin_amdgcn_global_load_lds(
                (const __attribute__((address_space(1))) unsigned int*)gb,
                (__attribute__((address_space(3))) unsigned int*)&Bb[buf][(c0 + i) * 16][0],
                16, 0, 0);
        }
    };

    STAGE(0, 0);
    __syncthreads();
    int kb = lane >> 4, lr = lane & 15;
    for (int t = 0; t < nt; ++t) {
        int buf = t & 1;
        if (t + 1 < nt) STAGE(t + 1, buf ^ 1);
        short8 af[4], bfr[4];
#pragma unroll
        for (int i = 0; i < 4; ++i)
            af[i] = *(const short8*)&Ab[buf][wr * 64 + i * 16 + lr][kb * 8];
#pragma unroll
        for (int j = 0; j < 4; ++j)
            bfr[j] = *(const short8*)&Bb[buf][wc * 64 + j * 16 + lr][kb * 8];
#pragma unroll
        for (int i = 0; i < 4; ++i)
#pragma unroll
            for (int j = 0; j < 4; ++j)
                acc[i][j] = __builtin_amdgcn_mfma_f32_16x16x32_bf16(
                    af[i], bfr[j], acc[i][j], 0, 0, 0);
        __syncthreads();
    }
    int rg = lane >> 4;
#pragma unroll
    for (int j = 0; j < 4; ++j) {
        int col = bn + wc * 64 + j * 16 + lr;
        float bcv = (BIASMODE == 1) ? bias[col] : 0.f;
        float ps = 0.f, pq = 0.f;
#pragma unroll
        for (int i = 0; i < 4; ++i) {
            int row0 = bm + wr * 64 + i * 16 + rg * 4;
#pragma unroll
            for (int r = 0; r < 4; ++r) {
                float v = acc[i][j][r];
                if (BIASMODE == 1) v += bcv;
                if (BIASMODE == 2) v += bias[row0 + r];
                if (ACT) v = fmaxf(v, 0.f);
                if (OUTF32)
                    ((float*)Cv)[coff + (size_t)(row0 + r) * ldc + col] = v;
                else
                    ((unsigned short*)Cv)[coff + (size_t)(row0 + r) * ldc + col] = f2bf(v);
                if (BNACC) { ps += v; pq += v * v; }
            }
        }
        if (BNACC) {
            ps += __shfl_xor(ps, 16); ps += __shfl_xor(ps, 32);
            pq += __shfl_xor(pq, 16); pq += __shfl_xor(pq, 32);
            if (rg == 0) {
                atomicAdd(&bnacc[col], ps);
                atomicAdd(&bnacc[FCH + col], pq);
            }
        }
    }
}

// ---------------- fused layer-1 + sparse layer-2 aggregate ----------------
// XCD-swizzled linear grid (1024): b=(i&7)+8*(i>>5), hq=(i>>3)&3.
__global__ __launch_bounds__(256) void k_l1t1(
    const unsigned short* __restrict__ Anb,
    const int* __restrict__ nidx,
    const unsigned short* __restrict__ T0,
    const unsigned short* __restrict__ W1T,
    const float* __restrict__ b1,
    unsigned short* __restrict__ T1r) {
    int bi = blockIdx.x;
    int b = (bi & 7) + 8 * (bi >> 5);
    int hq = (bi >> 3) & 3;
    int tid = threadIdx.x, w = tid >> 6, lane = tid & 63;
    int lr = lane & 15, kb = lane >> 4, rg = lane >> 4;
    __shared__ unsigned short Asub[NCAP * 256];   // 32 KB, rows XOR-swizzled
    __shared__ unsigned short T0s[2][64 * 64];    // 2 x 8 KB, src-swizzled
    __shared__ unsigned short X1s[128 * 64];      // 16 KB, rows XOR-swizzled
    for (int c = tid; c < NCAP * 32; c += 256) {
        int s = c >> 5, q = c & 31;
        int m = nidx[b * NCAP + s];
        uint4 v = *(const uint4*)(Anb + (size_t)m * 256 + q * 8);
        *(uint4*)((char*)Asub + s * 512 + ((q * 16) ^ ((s & 7) << 4))) = v;
    }
    short8 wfr[8][2];
    float b1v[8];
#pragma unroll
    for (int hj = 0; hj < 8; ++hj) {
        int h = hq * 128 + hj * 16 + lr;
        b1v[hj] = b1[h];
#pragma unroll
        for (int ks = 0; ks < 2; ++ks)
            wfr[hj][ks] = *(const short8*)(W1T + (size_t)h * 64 + ks * 32 + kb * 8);
    }
    auto STAGE = [&](int q, int buf) {
#pragma unroll
        for (int j = 0; j < 2; ++j) {
            int slot = j * 4 + w;
            int mloc = slot * 8 + (lane >> 3);
            int qg = (lane & 7) ^ (lane >> 3);
            const unsigned short* src =
                T0 + (size_t)(q * 64 + mloc) * (B_ * 64) + b * 64 + qg * 8;
            __builtin_amdgcn_global_load_lds(
                (const __attribute__((address_space(1))) unsigned int*)src,
                (__attribute__((address_space(3))) unsigned int*)(&T0s[buf][slot * 512]),
                16, 0, 0);
        }
    };
    STAGE(0, 0);
    __syncthreads();
    f32x4 acc2[4][2] = {};
    int buf = 0;
    for (int q = 0; q < 4; ++q) {
        if (q < 3) STAGE(q + 1, buf ^ 1);
        f32x4 acc[8] = {};
        const char* t0b = (const char*)&T0s[buf][0];
#pragma unroll
        for (int ks = 0; ks < 2; ++ks) {
            short8 af = *(const short8*)(t0b + (w * 16 + lr) * 128 +
                                         ((ks * 64 + kb * 16) ^ ((lr & 7) << 4)));
#pragma unroll
            for (int hj = 0; hj < 8; ++hj)
                acc[hj] = __builtin_amdgcn_mfma_f32_16x16x32_bf16(
                    af, wfr[hj][ks], acc[hj], 0, 0, 0);
        }
        asm volatile("s_waitcnt vmcnt(0)" ::: "memory");
        __syncthreads();
#pragma unroll
        for (int hj = 0; hj < 8; ++hj) {
            int h = hj * 16 + lr;
            unsigned short pk[4];
#pragma unroll
            for (int r = 0; r < 4; ++r)
                pk[r] = f2bf(fmaxf(acc[hj][r] + b1v[hj], 0.f));
            int m0 = w * 16 + rg * 4;
            *(uint2*)((char*)X1s + h * 128 + ((m0 * 2) ^ ((h & 7) << 4))) = *(uint2*)pk;
        }
        __syncthreads();
#pragma unroll
        for (int ks2 = 0; ks2 < 2; ++ks2) {
            short8 af2[4];
#pragma unroll
            for (int ai = 0; ai < 4; ++ai)
                af2[ai] = *(const short8*)((char*)Asub + (ai * 16 + lr) * 512 +
                                           ((q * 128 + ks2 * 64 + kb * 16) ^ ((lr & 7) << 4)));
#pragma unroll
            for (int hj2 = 0; hj2 < 2; ++hj2) {
                int h = w * 32 + hj2 * 16 + lr;
                short8 bf2 = *(const short8*)((char*)X1s + h * 128 +
                                              ((ks2 * 64 + kb * 16) ^ ((h & 7) << 4)));
#pragma unroll
                for (int ai = 0; ai < 4; ++ai)
                    acc2[ai][hj2] = __builtin_amdgcn_mfma_f32_16x16x32_bf16(
                        af2[ai], bf2, acc2[ai][hj2], 0, 0, 0);
            }
        }
        __syncthreads();
        buf ^= 1;
    }
#pragma unroll
    for (int hj2 = 0; hj2 < 2; ++hj2) {
        int h = hq * 128 + w * 32 + hj2 * 16 + lr;
#pragma unroll
        for (int ai = 0; ai < 4; ++ai) {
#pragma unroll
            for (int r = 0; r < 4; ++r) {
                int i = ai * 16 + rg * 4 + r;
                T1r[(size_t)(b * NCAP + i) * H1 + h] = f2bf(acc2[ai][hj2][r]);
            }
        }
    }
}

// ---------------- x2 GEMM + fused weighted reduction -> y ----------------
__global__ __launch_bounds__(256) void k_x2y(
    const unsigned short* __restrict__ T1r,
    const unsigned short* __restrict__ W2T,
    const float* __restrict__ b2,
    const float* __restrict__ nw,
    unsigned short* __restrict__ y) {
    __shared__ unsigned short Ab[2][128][32];
    __shared__ unsigned short Bb[2][128][32];
    int tid = threadIdx.x;
    int i0 = blockIdx.x;
    int bm = ((i0 & 7) + 8 * (i0 >> 5)) * 128;
    int bn = ((i0 >> 3) & 3) * 128;
    int wid = tid >> 6, lane = tid & 63;
    int wr = wid >> 1, wc = wid & 1;
    int c0 = wid * 2;
    int lrow = lane >> 2, lkq = lane & 3;
    f32x4 acc[4][4] = {};
    const int nt = H1 / 32;   // K=512
    auto STAGE = [&](int t, int buf) {
        int k0 = t * 32;
#pragma unroll
        for (int i = 0; i < 2; ++i) {
            int row = (c0 + i) * 16 + lrow;
            const unsigned short* ga = T1r + (size_t)(bm + row) * H1 + k0 + lkq * 8;
            __builtin_amdgcn_global_load_lds(
                (const __attribute__((address_space(1))) unsigned int*)ga,
                (__attribute__((address_space(3))) unsigned int*)&Ab[buf][(c0 + i) * 16][0],
                16, 0, 0);
            const unsigned short* gb = W2T + (size_t)(bn + row) * H1 + k0 + lkq * 8;
            __builtin_amdgcn_global_load_lds(
                (const __attribute__((address_space(1))) unsigned int*)gb,
                (__attribute__((address_space(3))) unsigned int*)&Bb[buf][(c0 + i) * 16][0],
                16, 0, 0);
        }
    };
    STAGE(0, 0);
    __syncthreads();
    int kb = lane >> 4, lr = lane & 15;
    for (int t = 0; t < nt; ++t) {
        int buf = t & 1;
        if (t + 1 < nt) STAGE(t + 1, buf ^ 1);
        short8 af[4], bfr[4];
#pragma unroll
        for (int i = 0; i < 4; ++i)
            af[i] = *(const short8*)&Ab[buf][wr * 64 + i * 16 + lr][kb * 8];
#pragma unroll
        for (int j = 0; j < 4; ++j)
            bfr[j] = *(const short8*)&Bb[buf][wc * 64 + j * 16 + lr][kb * 8];
#pragma unroll
        for (int i = 0; i < 4; ++i)
#pragma unroll
            for (int j = 0; j < 4; ++j)
                acc[i][j] = __builtin_amdgcn_mfma_f32_16x16x32_bf16(
                    af[i], bfr[j], acc[i][j], 0, 0, 0);
        __syncthreads();
    }
    int rg = lane >> 4;
    int s = (bm >> 6) + wr;
    float wv[4][4];
#pragma unroll
    for (int i = 0; i < 4; ++i)
#pragma unroll
        for (int r = 0; r < 4; ++r)
            wv[i][r] = nw[s * NCAP + i * 16 + rg * 4 + r];
#pragma unroll
    for (int j = 0; j < 4; ++j) {
        int col = bn + wc * 64 + j * 16 + lr;
        float bcv = b2[col];
        float p = 0.f;
#pragma unroll
        for (int i = 0; i < 4; ++i)
#pragma unroll
            for (int r = 0; r < 4; ++r)
                p += wv[i][r] * fmaxf(acc[i][j][r] + bcv, 0.f);
        p += __shfl_xor(p, 16);
        p += __shfl_xor(p, 32);
        if (rg == 0) y[(size_t)s * H1 + col] = f2bf(p);
    }
}

// ---------------- BN(from sums) + LeakyReLU + final Linear + sigmoid ----------------
__global__ void k_head(const float* __restrict__ h, const float* __restrict__ mv,
                       const float* __restrict__ gamma, const float* __restrict__ beta,
                       const float* __restrict__ fcW2, const float* __restrict__ fcb2,
                       float* __restrict__ out) {
    int b = blockIdx.x, t = threadIdx.x;
    float mean = mv[t] * (1.f / B_);
    float rstd = rsqrtf(mv[FCH + t] * (1.f / B_) - mean * mean + 1e-5f);
    float v = h[(size_t)b * FCH + t];
    v = (v - mean) * rstd * gamma[t] + beta[t];
    v = (v >= 0.f) ? v : 0.01f * v;
    float p = v * fcW2[t];
    __shared__ float red[8];
    for (int off = 32; off; off >>= 1) p += __shfl_down(p, off);
    if ((t & 63) == 0) red[t >> 6] = p;
    __syncthreads();
    if (t == 0) {
        float s = fcb2[0];
#pragma unroll
        for (int i = 0; i < 8; ++i) s += red[i];
        out[b] = 1.f / (1.f + expf(-s));
    }
}

static inline size_t align256(size_t x) { return (x + 255) & ~(size_t)255; }

extern "C" void kernel_launch(void* const* d_in, const int* in_sizes, int n_in,
                              void* d_out, int out_size, void* d_ws, size_t ws_size,
                              hipStream_t stream) {
    const float* x     = (const float*)d_in[0];
    const float* adj   = (const float*)d_in[1];
    const float* W1    = (const float*)d_in[2];
    const float* b1    = (const float*)d_in[3];
    const float* W2    = (const float*)d_in[4];
    const float* b2    = (const float*)d_in[5];
    const float* W3    = (const float*)d_in[6];
    const float* b3    = (const float*)d_in[7];
    const float* fcW1  = (const float*)d_in[8];
    const float* fcb1  = (const float*)d_in[9];
    const float* gamma = (const float*)d_in[10];
    const float* beta  = (const float*)d_in[11];
    const float* fcW2  = (const float*)d_in[12];
    const float* fcb2  = (const float*)d_in[13];
    float* out = (float*)d_out;

    char* ws = (char*)d_ws;
    size_t off = 0;
    auto alloc = [&](size_t bytes) { char* p = ws + off; off += align256(bytes); return p; };
    unsigned short* Anb   = (unsigned short*)alloc((size_t)N_ * N_ * 2);
    int*            nidx  = (int*)alloc((size_t)B_ * NCAP * 4);
    float*          nw    = (float*)alloc((size_t)B_ * NCAP * 4);
    unsigned short* W1T   = (unsigned short*)alloc((size_t)H1 * 64 * 2);
    unsigned short* W2T   = (unsigned short*)alloc((size_t)H1 * H1 * 2);
    unsigned short* W3T   = (unsigned short*)alloc((size_t)H2 * H1 * 2);
    unsigned short* fcW1T = (unsigned short*)alloc((size_t)H1 * H2 * 2);
    unsigned short* y     = (unsigned short*)alloc((size_t)B_ * H1 * 2);
    unsigned short* g     = (unsigned short*)alloc((size_t)B_ * H2 * 2);
    float*          h     = (float*)alloc((size_t)B_ * FCH * 4);
    float*          mv    = (float*)alloc((size_t)1024 * 4);
    unsigned short* Xs    = (unsigned short*)alloc((size_t)N_ * B_ * 64 * 2);    // 8 MB
    unsigned short* T0    = (unsigned short*)alloc((size_t)N_ * B_ * 64 * 2);    // 8 MB
    unsigned short* T1r   = (unsigned short*)alloc((size_t)B_ * NCAP * H1 * 2);  // 16 MB
    if (off > ws_size) return;   // ~36 MB needed

    // 1: transposes + An + neighbor lists + scatter + mv zero (one launch)
    k_init<<<4096 + N_ + B_ / 4 + 1 + B_, 256, 0, stream>>>(
        W1, W2, W3, fcW1, adj, x, W1T, W2T, W3T, fcW1T, mv, Anb, nidx, nw, Xs);
    // 2: GEMM0: T0[n][(b,f)] = An @ Xs   M=256, N=B*64, K=256
    bgemm<0, 0><<<dim3((B_ * 64) / 128, 2), 256, 0, stream>>>(
        Anb, Xs, nullptr, T0, N_, N_, B_ * 64, B_ * 64);
    // 3: fused layer1 + sparse aggregate (XCD-swizzled grid)
    k_l1t1<<<B_ * 4, 256, 0, stream>>>(Anb, nidx, T0, W1T, b1, T1r);
    // 4: x2 + weighted reduce -> y (XCD-swizzled grid)
    k_x2y<<<(B_ * NCAP / 128) * (H1 / 128), 256, 0, stream>>>(
        T1r, W2T, b2, nw, y);
    // 5: GEMM4: g = relu(y @ W3T^T + b3)   256x1024x512
    btgemm<1, 1, 0, 0><<<dim3(H2 / 128, B_ / 128), 256, 0, stream>>>(
        y, W3T, b3, g, nullptr, H1, H1, H1, H2, 20, 0, 0);
    // 6: GEMM5: h = g @ fcW1T^T + fcb1 (f32) + BN sum/sumsq atomics
    btgemm<0, 1, 1, 1><<<dim3(FCH / 128, B_ / 128), 256, 0, stream>>>(
        g, fcW1T, fcb1, h, mv, H2, H2, H2, FCH, 20, 0, 0);
    // 7: BN + LeakyReLU + fc2 + sigmoid
    k_head<<<B_, FCH, 0, stream>>>(h, mv, gamma, beta, fcW2, fcb2, out);
}

// Round 14
// 103.332 us; speedup vs baseline: 1.0953x; 1.0953x over previous
//
#include <hip/hip_runtime.h>
#include <cstdint>
#include <initializer_list>

// Problem constants
#define B_   256   // BATCH
#define N_   256   // NODE_NUM
#define S_   128   // SEQ_LEN
#define Fm1  63    // FEATURE_NUM-1
#define XROW 65    // FEATURE_NUM+1 (x last-dim)
#define H1   512   // HIDDEN/2
#define H2   1024  // HIDDEN
#define FCH  512   // FC_HIDDEN
#define NCAP 64    // neighbor capacity (cnt ~26 +- 4.7; 64 is ~8 sigma)

typedef __attribute__((ext_vector_type(8))) short short8;
typedef __attribute__((ext_vector_type(4))) float f32x4;

__device__ __forceinline__ unsigned short f2bf(float f) {
    union { float f; unsigned u; } v; v.f = f;
    unsigned r = v.u + 0x7FFF + ((v.u >> 16) & 1);   // RNE
    return (unsigned short)(r >> 16);
}
__device__ __forceinline__ float bf2f(unsigned short u) {
    union { unsigned u; float f; } v; v.u = ((unsigned)u) << 16;
    return v.f;
}

// ---------------- single init launch ----------------
// blocks [0,4096):        weight transposes (z = blk>>10, by, bx)
// blocks [4096,4352):     An row n = blk-4096 (local dinv, COALESCED col-sum)
// blocks [4352,4416):     neighbor lists, 4 samples each (local dinv)
// block  4416:            zero BN accumulators
// blocks [4417,4673):     zero+scatter sample b = blk-4417
__global__ void k_init(const float* __restrict__ W1, const float* __restrict__ W2,
                       const float* __restrict__ W3, const float* __restrict__ fcW1,
                       const float* __restrict__ adj, const float* __restrict__ x,
                       unsigned short* __restrict__ W1T, unsigned short* __restrict__ W2T,
                       unsigned short* __restrict__ W3T, unsigned short* __restrict__ fcW1T,
                       float* __restrict__ mv,
                       unsigned short* __restrict__ Anb,
                       int* __restrict__ nidx, float* __restrict__ nw,
                       unsigned short* __restrict__ Xs) {
    int blk = blockIdx.x;
    int tid = threadIdx.x;
    if (blk < 4096) {
        // ---- weight transpose ----
        const float* in; unsigned short* out; int R_in, C_in, R_pad;
        switch (blk >> 10) {
            case 0:  in = W1;   out = W1T;   R_in = Fm1; C_in = H1; R_pad = 64;  break;
            case 1:  in = W2;   out = W2T;   R_in = H1;  C_in = H1; R_pad = H1;  break;
            case 2:  in = W3;   out = W3T;   R_in = H1;  C_in = H2; R_pad = H1;  break;
            default: in = fcW1; out = fcW1T; R_in = H2;  C_in = H1; R_pad = H2;  break;
        }
        int r0 = ((blk >> 5) & 31) * 32, c0 = (blk & 31) * 32;
        if (r0 >= R_pad || c0 >= C_in) return;
        __shared__ float tile[32][33];
        int tr = tid >> 5, tc = tid & 31;   // 8 x 32
#pragma unroll
        for (int rr = 0; rr < 4; ++rr) {
            int r = r0 + tr + rr * 8;
            tile[tr + rr * 8][tc] = (r < R_in) ? in[(size_t)r * C_in + c0 + tc] : 0.f;
        }
        __syncthreads();
#pragma unroll
        for (int rr = 0; rr < 4; ++rr) {
            int c = c0 + tr + rr * 8;
            int r = r0 + tc;
            out[(size_t)c * R_pad + r] = f2bf(tile[tc][tr + rr * 8]);
        }
        return;
    }
    if (blk < 4416) {
        // ---- An rows / neighbor lists, block-local dinv via COALESCED column sums ----
        // adj is symmetric (maximum(adj, adj^T)) so col sum == row sum.
        __shared__ float dl[N_];
        {
            float s = 0.f;
#pragma unroll 8
            for (int m = 0; m < N_; ++m)
                s += adj[(size_t)m * N_ + tid];   // lane-contiguous per iteration
            dl[tid] = rsqrtf(s + 1.0f);   // deterministic, identical in every block
        }
        __syncthreads();
        if (blk < 4352) {
            int n = blk - 4096;
            float a = adj[n * N_ + tid] + (n == tid ? 1.f : 0.f);
            Anb[n * N_ + tid] = f2bf(a * dl[n] * dl[tid]);
        } else {
            int w = tid >> 6, lane = tid & 63;
            int b = (blk - 4352) * 4 + w;
            int g = (int)x[((size_t)b * S_ + S_ - 1) * XROW + (XROW - 2)];
            float dg = dl[g];
            int base = 0;
            for (int c = 0; c < 4; ++c) {
                int m = c * 64 + lane;
                float a = adj[g * N_ + m] + (g == m ? 1.f : 0.f);
                float v = a * dg * dl[m];   // identical expression to the An path
                unsigned long long mask = __ballot(v != 0.f);
                int pos = __popcll(mask & ((1ull << lane) - 1ull));
                if (v != 0.f) {
                    int s = base + pos;
                    if (s < NCAP) { nidx[b * NCAP + s] = m; nw[b * NCAP + s] = v; }
                }
                base += __popcll(mask);
            }
            for (int s = base + lane; s < NCAP; s += 64) {
                nidx[b * NCAP + s] = 0;
                nw[b * NCAP + s] = 0.f;
            }
        }
        return;
    }
    if (blk == 4416) {
        for (int k = tid; k < 1024; k += 256) mv[k] = 0.f;
        return;
    }
    // ---- zero+scatter: block writes ALL 256 node rows of sample b ----
    int b = blk - 4417;
    __shared__ short pres[N_];   // node -> seq index j, or -1
    pres[tid] = -1;
    __syncthreads();
    if (tid < S_) {
        int s = (int)x[((size_t)b * S_ + tid) * XROW + (XROW - 2)];
        pres[s] = (short)tid;    // sid unique per sample (permutation slice)
    }
    __syncthreads();
#pragma unroll
    for (int pass = 0; pass < 8; ++pass) {
        int m = pass * 32 + (tid >> 3);
        int f8 = tid & 7;
        int j = pres[m];
        unsigned short o[8];
        if (j >= 0) {
            const float* src = x + ((size_t)b * S_ + j) * XROW + f8 * 8;
#pragma unroll
            for (int i = 0; i < 8; ++i) {
                int f = f8 * 8 + i;
                o[i] = (f < Fm1) ? f2bf(src[i]) : (unsigned short)0;
            }
        } else {
#pragma unroll
            for (int i = 0; i < 8; ++i) o[i] = 0;
        }
        *(uint4*)(Xs + ((size_t)m * B_ + b) * 64 + f8 * 8) = *(uint4*)o;
    }
}

// ---------------- packing bgemm (GEMM0 only: B row-major [K,N]) ----------------
template <int ACT, int BIAS>
__global__ __launch_bounds__(256) void bgemm(const unsigned short* __restrict__ A,
                                             const unsigned short* __restrict__ B,
                                             const float* __restrict__ bias,
                                             unsigned short* __restrict__ C,
                                             int K, int lda, int ldb, int ldc) {
    __shared__ unsigned short Abuf[2][4][128][8];
    __shared__ unsigned short Bbuf[2][4][128][8];
    int tid = threadIdx.x;
    int bm = blockIdx.y * 128, bn = blockIdx.x * 128;
    int wid = tid >> 6, lane = tid & 63;
    int wr = wid >> 1, wc = wid & 1;
    int arow = tid >> 1, ahalf = tid & 1;
    int bcol = (tid & 63) * 2, bkb = tid >> 6;
    f32x4 acc[4][4] = {};
    uint4 areg0, areg1;
    unsigned br0[4], br1[4];
    const int nt = K / 32;
    auto gload = [&](int t) {
        int k0 = t * 32;
        const unsigned short* ap = A + (size_t)(bm + arow) * lda + k0 + ahalf * 16;
        areg0 = *(const uint4*)(ap);
        areg1 = *(const uint4*)(ap + 8);
        const unsigned short* bp = B + (size_t)(k0 + bkb * 8) * ldb + bn + bcol;
#pragma unroll
        for (int jj = 0; jj < 4; ++jj) {
            unsigned lo = *(const unsigned*)(bp);
            unsigned hi = *(const unsigned*)(bp + ldb);
            br0[jj] = (lo & 0xffffu) | (hi << 16);
            br1[jj] = (lo >> 16) | (hi & 0xffff0000u);
            bp += 2 * (size_t)ldb;
        }
    };
    auto swrite = [&](int buf) {
        *(uint4*)(&Abuf[buf][ahalf * 2 + 0][arow][0]) = areg0;
        *(uint4*)(&Abuf[buf][ahalf * 2 + 1][arow][0]) = areg1;
        *(uint4*)(&Bbuf[buf][bkb][bcol][0]) = *(uint4*)br0;
        *(uint4*)(&Bbuf[buf][bkb][bcol + 1][0]) = *(uint4*)br1;
    };
    gload(0);
    swrite(0);
    __syncthreads();
    for (int t = 0; t < nt; ++t) {
        if (t + 1 < nt) gload(t + 1);
        int buf = t & 1;
        int kb = lane >> 4, lr = lane & 15;
        short8 af[4], bfr[4];
#pragma unroll
        for (int i = 0; i < 4; ++i)
            af[i] = *(const short8*)(&Abuf[buf][kb][wr * 64 + i * 16 + lr][0]);
#pragma unroll
        for (int j = 0; j < 4; ++j)
            bfr[j] = *(const short8*)(&Bbuf[buf][kb][wc * 64 + j * 16 + lr][0]);
#pragma unroll
        for (int i = 0; i < 4; ++i)
#pragma unroll
            for (int j = 0; j < 4; ++j)
                acc[i][j] = __builtin_amdgcn_mfma_f32_16x16x32_bf16(
                    af[i], bfr[j], acc[i][j], 0, 0, 0);
        if (t + 1 < nt) swrite(buf ^ 1);
        __syncthreads();
    }
    int lr = lane & 15, rg = lane >> 4;
#pragma unroll
    for (int j = 0; j < 4; ++j) {
        int col = bn + wc * 64 + j * 16 + lr;
        float bv = BIAS ? bias[col] : 0.f;
#pragma unroll
        for (int i = 0; i < 4; ++i) {
            int row0 = bm + wr * 64 + i * 16 + rg * 4;
#pragma unroll
            for (int r = 0; r < 4; ++r) {
                float v = acc[i][j][r] + bv;
                if (ACT) v = fmaxf(v, 0.f);
                C[(size_t)(row0 + r) * ldc + col] = f2bf(v);
            }
        }
    }
}

// ---------------- bt-GEMM (m97 structure): C = act(A @ B^T + bias) ----------------
// BNACC: epilogue accumulates per-column sum/sumsq into bnacc[col], bnacc[FCH+col]
template <int ACT, int BIASMODE, int OUTF32, int BNACC>
__global__ __launch_bounds__(256) void btgemm(const unsigned short* __restrict__ A,
                                              const unsigned short* __restrict__ Bm,
                                              const float* __restrict__ bias,
                                              void* __restrict__ Cv,
                                              float* __restrict__ bnacc,
                                              int K, int lda, int ldb, int ldc,
                                              int ns, int sb, int sc) {
    __shared__ unsigned short Ab[2][128][32];
    __shared__ unsigned short Bb[2][128][32];
    int tid = threadIdx.x;
    int bm = blockIdx.y * 128;
    int bx = blockIdx.x;
    int sample = bx >> ns;
    int bn = (bx & ((1 << ns) - 1)) * 128;
    const unsigned short* Bp = Bm + (size_t)sample * sb;
    size_t coff = (size_t)sample * sc;

    int wid = tid >> 6, lane = tid & 63;
    int wr = wid >> 1, wc = wid & 1;
    int c0 = wid * 2;
    int lrow = lane >> 2, lkq = lane & 3;

    f32x4 acc[4][4] = {};
    const int nt = K / 32;

    auto STAGE = [&](int t, int buf) {
        int k0 = t * 32;
#pragma unroll
        for (int i = 0; i < 2; ++i) {
            int row = (c0 + i) * 16 + lrow;
            const unsigned short* ga = A + (size_t)(bm + row) * lda + k0 + lkq * 8;
            __builtin_amdgcn_global_load_lds(
                (const __attribute__((address_space(1))) unsigned int*)ga,
                (__attribute__((address_space(3))) unsigned int*)&Ab[buf][(c0 + i) * 16][0],
                16, 0, 0);
            const unsigned short* gb = Bp + (size_t)(bn + row) * ldb + k0 + lkq * 8;
            __builtin_amdgcn_global_load_lds(
                (const __attribute__((address_space(1))) unsigned int*)gb,
                (__attribute__((address_space(3))) unsigned int*)&Bb[buf][(c0 + i) * 16][0],
                16, 0, 0);
        }
    };

    STAGE(0, 0);
    __syncthreads();
    int kb = lane >> 4, lr = lane & 15;
    for (int t = 0; t < nt; ++t) {
        int buf = t & 1;
        if (t + 1 < nt) STAGE(t + 1, buf ^ 1);
        short8 af[4], bfr[4];
#pragma unroll
        for (int i = 0; i < 4; ++i)
            af[i] = *(const short8*)&Ab[buf][wr * 64 + i * 16 + lr][kb * 8];
#pragma unroll
        for (int j = 0; j < 4; ++j)
            bfr[j] = *(const short8*)&Bb[buf][wc * 64 + j * 16 + lr][kb * 8];
#pragma unroll
        for (int i = 0; i < 4; ++i)
#pragma unroll
            for (int j = 0; j < 4; ++j)
                acc[i][j] = __builtin_amdgcn_mfma_f32_16x16x32_bf16(
                    af[i], bfr[j], acc[i][j], 0, 0, 0);
        __syncthreads();
    }
    int rg = lane >> 4;
#pragma unroll
    for (int j = 0; j < 4; ++j) {
        int col = bn + wc * 64 + j * 16 + lr;
        float bcv = (BIASMODE == 1) ? bias[col] : 0.f;
        float ps = 0.f, pq = 0.f;
#pragma unroll
        for (int i = 0; i < 4; ++i) {
            int row0 = bm + wr * 64 + i * 16 + rg * 4;
#pragma unroll
            for (int r = 0; r < 4; ++r) {
                float v = acc[i][j][r];
                if (BIASMODE == 1) v += bcv;
                if (BIASMODE == 2) v += bias[row0 + r];
                if (ACT) v = fmaxf(v, 0.f);
                if (OUTF32)
                    ((float*)Cv)[coff + (size_t)(row0 + r) * ldc + col] = v;
                else
                    ((unsigned short*)Cv)[coff + (size_t)(row0 + r) * ldc + col] = f2bf(v);
                if (BNACC) { ps += v; pq += v * v; }
            }
        }
        if (BNACC) {
            ps += __shfl_xor(ps, 16); ps += __shfl_xor(ps, 32);
            pq += __shfl_xor(pq, 16); pq += __shfl_xor(pq, 32);
            if (rg == 0) {
                atomicAdd(&bnacc[col], ps);
                atomicAdd(&bnacc[FCH + col], pq);
            }
        }
    }
}

// ---------------- fused layer-1 + sparse layer-2 aggregate ----------------
// XCD-swizzled linear grid (1024): b=(i&7)+8*(i>>5), hq=(i>>3)&3.
__global__ __launch_bounds__(256) void k_l1t1(
    const unsigned short* __restrict__ Anb,
    const int* __restrict__ nidx,
    const unsigned short* __restrict__ T0,
    const unsigned short* __restrict__ W1T,
    const float* __restrict__ b1,
    unsigned short* __restrict__ T1r) {
    int bi = blockIdx.x;
    int b = (bi & 7) + 8 * (bi >> 5);
    int hq = (bi >> 3) & 3;
    int tid = threadIdx.x, w = tid >> 6, lane = tid & 63;
    int lr = lane & 15, kb = lane >> 4, rg = lane >> 4;
    __shared__ unsigned short Asub[NCAP * 256];   // 32 KB, rows XOR-swizzled
    __shared__ unsigned short T0s[2][64 * 64];    // 2 x 8 KB, src-swizzled
    __shared__ unsigned short X1s[128 * 64];      // 16 KB, rows XOR-swizzled
    for (int c = tid; c < NCAP * 32; c += 256) {
        int s = c >> 5, q = c & 31;
        int m = nidx[b * NCAP + s];
        uint4 v = *(const uint4*)(Anb + (size_t)m * 256 + q * 8);
        *(uint4*)((char*)Asub + s * 512 + ((q * 16) ^ ((s & 7) << 4))) = v;
    }
    short8 wfr[8][2];
    float b1v[8];
#pragma unroll
    for (int hj = 0; hj < 8; ++hj) {
        int h = hq * 128 + hj * 16 + lr;
        b1v[hj] = b1[h];
#pragma unroll
        for (int ks = 0; ks < 2; ++ks)
            wfr[hj][ks] = *(const short8*)(W1T + (size_t)h * 64 + ks * 32 + kb * 8);
    }
    auto STAGE = [&](int q, int buf) {
#pragma unroll
        for (int j = 0; j < 2; ++j) {
            int slot = j * 4 + w;
            int mloc = slot * 8 + (lane >> 3);
            int qg = (lane & 7) ^ (lane >> 3);
            const unsigned short* src =
                T0 + (size_t)(q * 64 + mloc) * (B_ * 64) + b * 64 + qg * 8;
            __builtin_amdgcn_global_load_lds(
                (const __attribute__((address_space(1))) unsigned int*)src,
                (__attribute__((address_space(3))) unsigned int*)(&T0s[buf][slot * 512]),
                16, 0, 0);
        }
    };
    STAGE(0, 0);
    __syncthreads();
    f32x4 acc2[4][2] = {};
    int buf = 0;
    for (int q = 0; q < 4; ++q) {
        if (q < 3) STAGE(q + 1, buf ^ 1);
        f32x4 acc[8] = {};
        const char* t0b = (const char*)&T0s[buf][0];
#pragma unroll
        for (int ks = 0; ks < 2; ++ks) {
            short8 af = *(const short8*)(t0b + (w * 16 + lr) * 128 +
                                         ((ks * 64 + kb * 16) ^ ((lr & 7) << 4)));
#pragma unroll
            for (int hj = 0; hj < 8; ++hj)
                acc[hj] = __builtin_amdgcn_mfma_f32_16x16x32_bf16(
                    af, wfr[hj][ks], acc[hj], 0, 0, 0);
        }
        asm volatile("s_waitcnt vmcnt(0)" ::: "memory");
        __syncthreads();
#pragma unroll
        for (int hj = 0; hj < 8; ++hj) {
            int h = hj * 16 + lr;
            unsigned short pk[4];
#pragma unroll
            for (int r = 0; r < 4; ++r)
                pk[r] = f2bf(fmaxf(acc[hj][r] + b1v[hj], 0.f));
            int m0 = w * 16 + rg * 4;
            *(uint2*)((char*)X1s + h * 128 + ((m0 * 2) ^ ((h & 7) << 4))) = *(uint2*)pk;
        }
        __syncthreads();
#pragma unroll
        for (int ks2 = 0; ks2 < 2; ++ks2) {
            short8 af2[4];
#pragma unroll
            for (int ai = 0; ai < 4; ++ai)
                af2[ai] = *(const short8*)((char*)Asub + (ai * 16 + lr) * 512 +
                                           ((q * 128 + ks2 * 64 + kb * 16) ^ ((lr & 7) << 4)));
#pragma unroll
            for (int hj2 = 0; hj2 < 2; ++hj2) {
                int h = w * 32 + hj2 * 16 + lr;
                short8 bf2 = *(const short8*)((char*)X1s + h * 128 +
                                              ((ks2 * 64 + kb * 16) ^ ((h & 7) << 4)));
#pragma unroll
                for (int ai = 0; ai < 4; ++ai)
                    acc2[ai][hj2] = __builtin_amdgcn_mfma_f32_16x16x32_bf16(
                        af2[ai], bf2, acc2[ai][hj2], 0, 0, 0);
            }
        }
        __syncthreads();
        buf ^= 1;
    }
#pragma unroll
    for (int hj2 = 0; hj2 < 2; ++hj2) {
        int h = hq * 128 + w * 32 + hj2 * 16 + lr;
#pragma unroll
        for (int ai = 0; ai < 4; ++ai) {
#pragma unroll
            for (int r = 0; r < 4; ++r) {
                int i = ai * 16 + rg * 4 + r;
                T1r[(size_t)(b * NCAP + i) * H1 + h] = f2bf(acc2[ai][hj2][r]);
            }
        }
    }
}

// ---------------- x2 GEMM + fused weighted reduction -> y ----------------
__global__ __launch_bounds__(256) void k_x2y(
    const unsigned short* __restrict__ T1r,
    const unsigned short* __restrict__ W2T,
    const float* __restrict__ b2,
    const float* __restrict__ nw,
    unsigned short* __restrict__ y) {
    __shared__ unsigned short Ab[2][128][32];
    __shared__ unsigned short Bb[2][128][32];
    int tid = threadIdx.x;
    int i0 = blockIdx.x;
    int bm = ((i0 & 7) + 8 * (i0 >> 5)) * 128;
    int bn = ((i0 >> 3) & 3) * 128;
    int wid = tid >> 6, lane = tid & 63;
    int wr = wid >> 1, wc = wid & 1;
    int c0 = wid * 2;
    int lrow = lane >> 2, lkq = lane & 3;
    f32x4 acc[4][4] = {};
    const int nt = H1 / 32;   // K=512
    auto STAGE = [&](int t, int buf) {
        int k0 = t * 32;
#pragma unroll
        for (int i = 0; i < 2; ++i) {
            int row = (c0 + i) * 16 + lrow;
            const unsigned short* ga = T1r + (size_t)(bm + row) * H1 + k0 + lkq * 8;
            __builtin_amdgcn_global_load_lds(
                (const __attribute__((address_space(1))) unsigned int*)ga,
                (__attribute__((address_space(3))) unsigned int*)&Ab[buf][(c0 + i) * 16][0],
                16, 0, 0);
            const unsigned short* gb = W2T + (size_t)(bn + row) * H1 + k0 + lkq * 8;
            __builtin_amdgcn_global_load_lds(
                (const __attribute__((address_space(1))) unsigned int*)gb,
                (__attribute__((address_space(3))) unsigned int*)&Bb[buf][(c0 + i) * 16][0],
                16, 0, 0);
        }
    };
    STAGE(0, 0);
    __syncthreads();
    int kb = lane >> 4, lr = lane & 15;
    for (int t = 0; t < nt; ++t) {
        int buf = t & 1;
        if (t + 1 < nt) STAGE(t + 1, buf ^ 1);
        short8 af[4], bfr[4];
#pragma unroll
        for (int i = 0; i < 4; ++i)
            af[i] = *(const short8*)&Ab[buf][wr * 64 + i * 16 + lr][kb * 8];
#pragma unroll
        for (int j = 0; j < 4; ++j)
            bfr[j] = *(const short8*)&Bb[buf][wc * 64 + j * 16 + lr][kb * 8];
#pragma unroll
        for (int i = 0; i < 4; ++i)
#pragma unroll
            for (int j = 0; j < 4; ++j)
                acc[i][j] = __builtin_amdgcn_mfma_f32_16x16x32_bf16(
                    af[i], bfr[j], acc[i][j], 0, 0, 0);
        __syncthreads();
    }
    int rg = lane >> 4;
    int s = (bm >> 6) + wr;
    float wv[4][4];
#pragma unroll
    for (int i = 0; i < 4; ++i)
#pragma unroll
        for (int r = 0; r < 4; ++r)
            wv[i][r] = nw[s * NCAP + i * 16 + rg * 4 + r];
#pragma unroll
    for (int j = 0; j < 4; ++j) {
        int col = bn + wc * 64 + j * 16 + lr;
        float bcv = b2[col];
        float p = 0.f;
#pragma unroll
        for (int i = 0; i < 4; ++i)
#pragma unroll
            for (int r = 0; r < 4; ++r)
                p += wv[i][r] * fmaxf(acc[i][j][r] + bcv, 0.f);
        p += __shfl_xor(p, 16);
        p += __shfl_xor(p, 32);
        if (rg == 0) y[(size_t)s * H1 + col] = f2bf(p);
    }
}

// ---------------- BN(from sums) + LeakyReLU + final Linear + sigmoid ----------------
__global__ void k_head(const float* __restrict__ h, const float* __restrict__ mv,
                       const float* __restrict__ gamma, const float* __restrict__ beta,
                       const float* __restrict__ fcW2, const float* __restrict__ fcb2,
                       float* __restrict__ out) {
    int b = blockIdx.x, t = threadIdx.x;
    float mean = mv[t] * (1.f / B_);
    float rstd = rsqrtf(mv[FCH + t] * (1.f / B_) - mean * mean + 1e-5f);
    float v = h[(size_t)b * FCH + t];
    v = (v - mean) * rstd * gamma[t] + beta[t];
    v = (v >= 0.f) ? v : 0.01f * v;
    float p = v * fcW2[t];
    __shared__ float red[8];
    for (int off = 32; off; off >>= 1) p += __shfl_down(p, off);
    if ((t & 63) == 0) red[t >> 6] = p;
    __syncthreads();
    if (t == 0) {
        float s = fcb2[0];
#pragma unroll
        for (int i = 0; i < 8; ++i) s += red[i];
        out[b] = 1.f / (1.f + expf(-s));
    }
}

static inline size_t align256(size_t x) { return (x + 255) & ~(size_t)255; }

extern "C" void kernel_launch(void* const* d_in, const int* in_sizes, int n_in,
                              void* d_out, int out_size, void* d_ws, size_t ws_size,
                              hipStream_t stream) {
    const float* x     = (const float*)d_in[0];
    const float* adj   = (const float*)d_in[1];
    const float* W1    = (const float*)d_in[2];
    const float* b1    = (const float*)d_in[3];
    const float* W2    = (const float*)d_in[4];
    const float* b2    = (const float*)d_in[5];
    const float* W3    = (const float*)d_in[6];
    const float* b3    = (const float*)d_in[7];
    const float* fcW1  = (const float*)d_in[8];
    const float* fcb1  = (const float*)d_in[9];
    const float* gamma = (const float*)d_in[10];
    const float* beta  = (const float*)d_in[11];
    const float* fcW2  = (const float*)d_in[12];
    const float* fcb2  = (const float*)d_in[13];
    float* out = (float*)d_out;

    char* ws = (char*)d_ws;
    size_t off = 0;
    auto alloc = [&](size_t bytes) { char* p = ws + off; off += align256(bytes); return p; };
    unsigned short* Anb   = (unsigned short*)alloc((size_t)N_ * N_ * 2);
    int*            nidx  = (int*)alloc((size_t)B_ * NCAP * 4);
    float*          nw    = (float*)alloc((size_t)B_ * NCAP * 4);
    unsigned short* W1T   = (unsigned short*)alloc((size_t)H1 * 64 * 2);
    unsigned short* W2T   = (unsigned short*)alloc((size_t)H1 * H1 * 2);
    unsigned short* W3T   = (unsigned short*)alloc((size_t)H2 * H1 * 2);
    unsigned short* fcW1T = (unsigned short*)alloc((size_t)H1 * H2 * 2);
    unsigned short* y     = (unsigned short*)alloc((size_t)B_ * H1 * 2);
    unsigned short* g     = (unsigned short*)alloc((size_t)B_ * H2 * 2);
    float*          h     = (float*)alloc((size_t)B_ * FCH * 4);
    float*          mv    = (float*)alloc((size_t)1024 * 4);
    unsigned short* Xs    = (unsigned short*)alloc((size_t)N_ * B_ * 64 * 2);    // 8 MB
    unsigned short* T0    = (unsigned short*)alloc((size_t)N_ * B_ * 64 * 2);    // 8 MB
    unsigned short* T1r   = (unsigned short*)alloc((size_t)B_ * NCAP * H1 * 2);  // 16 MB
    if (off > ws_size) return;   // ~36 MB needed

    // 1: transposes + An + neighbor lists + scatter + mv zero (one launch)
    k_init<<<4096 + N_ + B_ / 4 + 1 + B_, 256, 0, stream>>>(
        W1, W2, W3, fcW1, adj, x, W1T, W2T, W3T, fcW1T, mv, Anb, nidx, nw, Xs);
    // 2: GEMM0: T0[n][(b,f)] = An @ Xs   M=256, N=B*64, K=256
    bgemm<0, 0><<<dim3((B_ * 64) / 128, 2), 256, 0, stream>>>(
        Anb, Xs, nullptr, T0, N_, N_, B_ * 64, B_ * 64);
    // 3: fused layer1 + sparse aggregate (XCD-swizzled grid)
    k_l1t1<<<B_ * 4, 256, 0, stream>>>(Anb, nidx, T0, W1T, b1, T1r);
    // 4: x2 + weighted reduce -> y (XCD-swizzled grid)
    k_x2y<<<(B_ * NCAP / 128) * (H1 / 128), 256, 0, stream>>>(
        T1r, W2T, b2, nw, y);
    // 5: GEMM4: g = relu(y @ W3T^T + b3)   256x1024x512
    btgemm<1, 1, 0, 0><<<dim3(H2 / 128, B_ / 128), 256, 0, stream>>>(
        y, W3T, b3, g, nullptr, H1, H1, H1, H2, 20, 0, 0);
    // 6: GEMM5: h = g @ fcW1T^T + fcb1 (f32) + BN sum/sumsq atomics
    btgemm<0, 1, 1, 1><<<dim3(FCH / 128, B_ / 128), 256, 0, stream>>>(
        g, fcW1T, fcb1, h, mv, H2, H2, H2, FCH, 20, 0, 0);
    // 7: BN + LeakyReLU + fc2 + sigmoid
    k_head<<<B_, FCH, 0, stream>>>(h, mv, gamma, beta, fcW2, fcb2, out);
}